// Round 6
// baseline (1643.421 us; speedup 1.0000x reference)
//
#include <hip/hip_runtime.h>
#include <math.h>

#define T_STEPS 24
#define BATCH   128
#define DGI     256
#define DHI     512
#define S_ITERS 3
#define LAMBDA  0.95f
#define ETA     0.5f
#define EPS_A   1e-6f
#define LN_EPS  1e-5f
#define EPS_N   1e-6f
#define HIST_MAX 23   // at most T-1 stored rank-1 terms

// ---------------------------------------------------------------------------
// Tiled transpose fp32: dst[c*R + r] = src[r*C + c].
// ---------------------------------------------------------------------------
__global__ void transpose_k(const float* __restrict__ src, float* __restrict__ dst,
                            int R, int C) {
    __shared__ float tile[32][33];
    const int tx = threadIdx.x & 31;
    const int ty = threadIdx.x >> 5;          // 0..7 (256 threads)
    const int c0 = blockIdx.x * 32;
    const int r0 = blockIdx.y * 32;
    #pragma unroll
    for (int i = 0; i < 32; i += 8)
        tile[ty + i][tx] = src[(size_t)(r0 + ty + i) * C + (c0 + tx)];
    __syncthreads();
    #pragma unroll
    for (int i = 0; i < 32; i += 8)
        dst[(size_t)(c0 + ty + i) * R + (r0 + tx)] = tile[tx][ty + i];
}

// ---------------------------------------------------------------------------
// zproj[b][t][i] = sum_j Wg[i][j] * z[t][b][j]  (round-4 version, row-major)
// ---------------------------------------------------------------------------
__global__ __launch_bounds__(512)
void zproj_k(const float* __restrict__ z_seq, const float* __restrict__ Wg,
             float* __restrict__ zp) {
    __shared__ __align__(16) float sh_z[8][DGI];
    const int b    = blockIdx.x;
    const int t0   = blockIdx.y * 8;
    const int tid  = threadIdx.x;
    const int lane = tid & 63;
    const int wave = tid >> 6;
    {
        const float4* src =
            (const float4*)(z_seq + ((size_t)(t0 + wave) * BATCH + b) * DGI);
        ((float4*)sh_z[wave])[lane] = src[lane];
    }
    __syncthreads();

    float acc[8];
    #pragma unroll
    for (int tt = 0; tt < 8; ++tt) acc[tt] = 0.f;
    const float4* wrow = (const float4*)(Wg + (size_t)tid * DGI);
    #pragma unroll 4
    for (int j4 = 0; j4 < DGI / 4; ++j4) {
        const float4 w = wrow[j4];
        #pragma unroll
        for (int tt = 0; tt < 8; ++tt) {
            const float4 z = ((const float4*)sh_z[tt])[j4];
            acc[tt] = fmaf(w.x, z.x, acc[tt]);
            acc[tt] = fmaf(w.y, z.y, acc[tt]);
            acc[tt] = fmaf(w.z, z.z, acc[tt]);
            acc[tt] = fmaf(w.w, z.w, acc[tt]);
        }
    }
    #pragma unroll
    for (int tt = 0; tt < 8; ++tt)
        zp[((size_t)b * T_STEPS + (t0 + tt)) * DHI + tid] = acc[tt];
}

// ---------------------------------------------------------------------------
// Recurrence body. MODE: 0=full  1=noGEMV  2=noDOTS  3=noSCAL  4=noLN
// (ablation stubs are block-uniform; control flow is data-independent so
//  stubbed-kernel timing isolates each phase's cost)
// ---------------------------------------------------------------------------
template<int MODE>
__device__ __forceinline__
void rnn_body(const float* __restrict__ zp,
              const float* __restrict__ WhT,    // WhT[j][i] fp32
              const float* __restrict__ b_h,
              const float* __restrict__ gamma,
              const float* __restrict__ beta,
              const float* __restrict__ alpha_fw,
              float* __restrict__ out) {
    __shared__ __align__(16) float  sh_hist[HIST_MAX][DHI];
    __shared__ __align__(16) float  sh_hs[2][DHI];
    __shared__ __align__(16) float  sh_G[HIST_MAX][64];
    __shared__ __align__(16) float4 sh_part[4][128];    // GEMV jg-partials
    __shared__ float  sh_coef[32];
    __shared__ float  sh_dot[32];
    __shared__ float2 sh_red[8];

    const int tid  = threadIdx.x;
    const int lane = tid & 63;
    const int wave = tid >> 6;
    const int b    = blockIdx.x;

    const float bh_r = b_h[tid];
    const float g_r  = gamma[tid];
    const float bt_r = beta[tid];

    float kpow;
    {
        const float a  = alpha_fw[0];
        const float ax = fabsf(a);
        const float sp = (ax > 20.f) ? ax : log1pf(expf(ax));
        kpow = (a >= 0.f) ? (1.f + sp) : (1.f / (1.f + sp));
    }

    for (int i = tid; i < HIST_MAX * 64; i += DHI) ((float*)sh_G)[i] = 0.f;
    __syncthreads();

    int   p = 0;
    float hs_i = 0.f, hbase_i = 0.f;

    for (int t = 0; t < T_STEPS; ++t) {
        const float zval = zp[((size_t)b * T_STEPS + t) * DHI + tid];
        if (MODE != 1 && t > 0) {
            const int i4 = tid & 127;
            const int jg = tid >> 7;
            const int jbase = jg * 128;
            const float4* __restrict__ w4 = (const float4*)WhT;
            const size_t wrow = (size_t)jbase * (DHI / 4) + i4;
            const float4* h4p = (const float4*)(sh_hs[p] + jbase);
            float4 acc = make_float4(0.f, 0.f, 0.f, 0.f);
            #pragma unroll 4
            for (int j4 = 0; j4 < 32; ++j4) {
                const float4 h4 = h4p[j4];
                const float4 wa = w4[wrow + (size_t)(4 * j4 + 0) * 128];
                const float4 wb = w4[wrow + (size_t)(4 * j4 + 1) * 128];
                const float4 wc = w4[wrow + (size_t)(4 * j4 + 2) * 128];
                const float4 wd = w4[wrow + (size_t)(4 * j4 + 3) * 128];
                acc.x = fmaf(wa.x, h4.x, fmaf(wb.x, h4.y, fmaf(wc.x, h4.z, fmaf(wd.x, h4.w, acc.x))));
                acc.y = fmaf(wa.y, h4.x, fmaf(wb.y, h4.y, fmaf(wc.y, h4.z, fmaf(wd.y, h4.w, acc.y))));
                acc.z = fmaf(wa.z, h4.x, fmaf(wb.z, h4.y, fmaf(wc.z, h4.z, fmaf(wd.z, h4.w, acc.z))));
                acc.w = fmaf(wa.w, h4.x, fmaf(wb.w, h4.y, fmaf(wc.w, h4.z, fmaf(wd.w, h4.w, acc.w))));
            }
            sh_part[jg][i4] = acc;
            __syncthreads();                              // barrier A
            const float* pp = (const float*)sh_part;
            hbase_i = bh_r + zval +
                      ((pp[tid] + pp[512 + tid]) + (pp[1024 + tid] + pp[1536 + tid]));
        } else {
            hbase_i = bh_r + zval;                        // t==0 or noGEMV
        }
        hs_i = fmaxf(hbase_i, 0.f);
        p ^= 1;
        sh_hs[p][tid] = hs_i;
        __syncthreads();                                  // barrier 1

        const int niter = (t == 0) ? 1 : S_ITERS;
        for (int it = 0; it < niter; ++it) {
            const float* hcur = sh_hs[p];

            if (MODE != 2) {
                float h8[8];
                #pragma unroll
                for (int q = 0; q < 8; ++q) h8[q] = hcur[lane + 64 * q];
                for (int s = wave; s <= t; s += 8) {
                    float d = 0.f;
                    if (s == t) {
                        #pragma unroll
                        for (int q = 0; q < 8; ++q) d = fmaf(h8[q], h8[q], d);
                    } else {
                        const float* vr = sh_hist[s];
                        #pragma unroll
                        for (int q = 0; q < 8; ++q) d = fmaf(vr[lane + 64 * q], h8[q], d);
                    }
                    #pragma unroll
                    for (int off = 32; off > 0; off >>= 1) d += __shfl_xor(d, off, 64);
                    if (lane == 0) sh_dot[s] = d;
                }
            } else {
                if (tid <= t) sh_dot[tid] = 1.0f;         // stub: keep downstream live
            }
            __syncthreads();                              // barrier 2

            float Ah = 0.f, alpha;
            if (MODE != 3) {
                float dl = 0.f, w_l = 0.f;
                if (lane < t) { dl = sh_dot[lane]; w_l = sh_coef[lane] * dl; }
                float gsum = 0.f;
                for (int s = 0; s < t; ++s) {
                    const float ws = sh_coef[s] * sh_dot[s];
                    gsum = fmaf(ws, sh_G[s][lane], gsum);
                    Ah   = fmaf(ws, sh_hist[s][tid], Ah);
                }
                float pa = w_l * dl;
                float pb = w_l * gsum;
                #pragma unroll
                for (int off = 32; off > 0; off >>= 1) {
                    pa += __shfl_xor(pa, off, 64);
                    pb += __shfl_xor(pb, off, 64);
                }
                const float n1 = fmaxf(sqrtf(sh_dot[t]), EPS_N);
                const float n2 = fmaxf(sqrtf(fmaxf(pb, 0.f)), EPS_N);
                float R = pa / (n1 * n2);
                R = fminf(fmaxf(R, 0.f), 1.f);
                alpha = 1.f - __powf(1.f - R, kpow);
            } else {
                alpha = 0.5f;                             // stub
            }

            const float y = (1.f - alpha * alpha) * hbase_i + alpha * Ah;

            float mean, rstd;
            if (MODE != 4) {
                float q0 = y, q1 = y * y;
                #pragma unroll
                for (int off = 32; off > 0; off >>= 1) {
                    q0 += __shfl_xor(q0, off, 64);
                    q1 += __shfl_xor(q1, off, 64);
                }
                if (lane == 0) sh_red[wave] = make_float2(q0, q1);
                __syncthreads();                          // barrier 3
                float s0 = 0.f, s1 = 0.f;
                #pragma unroll
                for (int w = 0; w < 8; ++w) {
                    const float2 r = sh_red[w];
                    s0 += r.x; s1 += r.y;
                }
                mean = s0 * (1.f / DHI);
                const float var = fmaf(s1, 1.f / DHI, -mean * mean);
                rstd = rsqrtf(var + LN_EPS);
            } else {
                mean = 0.f; rstd = 1.f;                   // stub
            }
            hs_i = fmaxf(fmaf((y - mean) * rstd, g_r, bt_r), 0.f);
            p ^= 1;
            sh_hs[p][tid] = hs_i;
            __syncthreads();                              // barrier 4
        }

        if (t < T_STEPS - 1) {
            // history append: Gram row + coef; overlaps next GEMV
            const float* hcur = sh_hs[p];
            float h8[8];
            #pragma unroll
            for (int q = 0; q < 8; ++q) h8[q] = hcur[lane + 64 * q];
            for (int s = wave; s <= t; s += 8) {
                float d = 0.f;
                if (s == t) {
                    #pragma unroll
                    for (int q = 0; q < 8; ++q) d = fmaf(h8[q], h8[q], d);
                } else {
                    const float* vr = sh_hist[s];
                    #pragma unroll
                    for (int q = 0; q < 8; ++q) d = fmaf(vr[lane + 64 * q], h8[q], d);
                }
                #pragma unroll
                for (int off = 32; off > 0; off >>= 1) d += __shfl_xor(d, off, 64);
                if (MODE == 3) asm volatile("" :: "v"(d));  // keep append work live
                if (lane == 0) {
                    if (s == t) {
                        sh_G[t][t] = d;
                        sh_coef[t] = ETA / (d + EPS_A);
                    } else {
                        sh_G[t][s] = d;
                        sh_G[s][t] = d;
                    }
                }
            }
            if (tid < t) sh_coef[tid] *= LAMBDA;
            sh_hist[t][tid] = hs_i;
        } else {
            out[(size_t)b * DHI + tid] = hs_i;
        }
    }
}

#define DECL_VARIANT(name, mode)                                               \
    __global__ __launch_bounds__(512)                                          \
    void name(const float* __restrict__ zp, const float* __restrict__ WhT,     \
              const float* __restrict__ b_h, const float* __restrict__ gamma,  \
              const float* __restrict__ beta, const float* __restrict__ af,    \
              float* __restrict__ out) {                                       \
        rnn_body<mode>(zp, WhT, b_h, gamma, beta, af, out);                    \
    }
DECL_VARIANT(rnn_full,   0)
DECL_VARIANT(rnn_nogemv, 1)
DECL_VARIANT(rnn_nodots, 2)
DECL_VARIANT(rnn_noscal, 3)
DECL_VARIANT(rnn_noln,   4)

// ---------------------------------------------------------------------------
// Fallback (ws too small): fully self-contained fp32 row-major path.
// ---------------------------------------------------------------------------
__global__ __launch_bounds__(512)
void corernn_fb(const float* __restrict__ z_seq, const float* __restrict__ Wh,
                const float* __restrict__ Wg, const float* __restrict__ b_h,
                const float* __restrict__ gamma, const float* __restrict__ beta,
                const float* __restrict__ alpha_fw, float* __restrict__ out) {
    __shared__ __align__(16) float sh_hist[HIST_MAX][DHI];
    __shared__ __align__(16) float sh_hs[2][DHI];
    __shared__ __align__(16) float sh_G[HIST_MAX][64];
    __shared__ float  sh_coef[32];
    __shared__ float  sh_dot[32];
    __shared__ float2 sh_red[8];
    __shared__ __align__(16) float sh_z[DGI];

    const int tid  = threadIdx.x;
    const int lane = tid & 63;
    const int wave = tid >> 6;
    const int b    = blockIdx.x;
    const float bh_r = b_h[tid];
    const float g_r  = gamma[tid];
    const float bt_r = beta[tid];
    float kpow;
    {
        const float a  = alpha_fw[0];
        const float ax = fabsf(a);
        const float sp = (ax > 20.f) ? ax : log1pf(expf(ax));
        kpow = (a >= 0.f) ? (1.f + sp) : (1.f / (1.f + sp));
    }
    for (int i = tid; i < HIST_MAX * 64; i += DHI) ((float*)sh_G)[i] = 0.f;
    if (tid < DGI) sh_z[tid] = z_seq[(size_t)b * DGI + tid];
    __syncthreads();

    int p = 0;
    float hs_i = 0.f, hbase_i = 0.f;
    for (int t = 0; t < T_STEPS; ++t) {
        float a0 = bh_r, a1 = 0.f, a2 = 0.f, a3 = 0.f;
        {
            const float4* wrow = (const float4*)(Wg + (size_t)tid * DGI);
            const float4* z4   = (const float4*)sh_z;
            #pragma unroll 4
            for (int j4 = 0; j4 < DGI / 4; ++j4) {
                const float4 w = wrow[j4]; const float4 h = z4[j4];
                a0 = fmaf(w.x, h.x, a0); a1 = fmaf(w.y, h.y, a1);
                a2 = fmaf(w.z, h.z, a2); a3 = fmaf(w.w, h.w, a3);
            }
        }
        if (t > 0) {
            const float4* wrow = (const float4*)(Wh + (size_t)tid * DHI);
            const float4* h4   = (const float4*)sh_hs[p];
            #pragma unroll 4
            for (int j4 = 0; j4 < DHI / 4; ++j4) {
                const float4 w = wrow[j4]; const float4 h = h4[j4];
                a0 = fmaf(w.x, h.x, a0); a1 = fmaf(w.y, h.y, a1);
                a2 = fmaf(w.z, h.z, a2); a3 = fmaf(w.w, h.w, a3);
            }
        }
        hbase_i = (a0 + a1) + (a2 + a3);
        hs_i = fmaxf(hbase_i, 0.f);
        p ^= 1; sh_hs[p][tid] = hs_i;
        __syncthreads();

        const int niter = (t == 0) ? 1 : S_ITERS;
        for (int it = 0; it < niter; ++it) {
            const float* hcur = sh_hs[p];
            float h8[8];
            #pragma unroll
            for (int q = 0; q < 8; ++q) h8[q] = hcur[lane + 64 * q];
            for (int s = wave; s <= t; s += 8) {
                float d = 0.f;
                if (s == t) {
                    #pragma unroll
                    for (int q = 0; q < 8; ++q) d = fmaf(h8[q], h8[q], d);
                } else {
                    const float* vr = sh_hist[s];
                    #pragma unroll
                    for (int q = 0; q < 8; ++q) d = fmaf(vr[lane + 64 * q], h8[q], d);
                }
                #pragma unroll
                for (int off = 32; off > 0; off >>= 1) d += __shfl_xor(d, off, 64);
                if (lane == 0) sh_dot[s] = d;
            }
            __syncthreads();
            float dl = 0.f, w_l = 0.f;
            if (lane < t) { dl = sh_dot[lane]; w_l = sh_coef[lane] * dl; }
            float gsum = 0.f, Ah = 0.f;
            for (int s = 0; s < t; ++s) {
                const float ws = sh_coef[s] * sh_dot[s];
                gsum = fmaf(ws, sh_G[s][lane], gsum);
                Ah   = fmaf(ws, sh_hist[s][tid], Ah);
            }
            float pa = w_l * dl, pb = w_l * gsum;
            #pragma unroll
            for (int off = 32; off > 0; off >>= 1) {
                pa += __shfl_xor(pa, off, 64);
                pb += __shfl_xor(pb, off, 64);
            }
            const float n1 = fmaxf(sqrtf(sh_dot[t]), EPS_N);
            const float n2 = fmaxf(sqrtf(fmaxf(pb, 0.f)), EPS_N);
            float R = fminf(fmaxf(pa / (n1 * n2), 0.f), 1.f);
            const float alpha = 1.f - __powf(1.f - R, kpow);
            const float y = (1.f - alpha * alpha) * hbase_i + alpha * Ah;
            float q0 = y, q1 = y * y;
            #pragma unroll
            for (int off = 32; off > 0; off >>= 1) {
                q0 += __shfl_xor(q0, off, 64);
                q1 += __shfl_xor(q1, off, 64);
            }
            if (lane == 0) sh_red[wave] = make_float2(q0, q1);
            __syncthreads();
            float s0 = 0.f, s1 = 0.f;
            #pragma unroll
            for (int w = 0; w < 8; ++w) { const float2 r = sh_red[w]; s0 += r.x; s1 += r.y; }
            const float mean = s0 * (1.f / DHI);
            const float var  = fmaf(s1, 1.f / DHI, -mean * mean);
            const float rstd = rsqrtf(var + LN_EPS);
            hs_i = fmaxf(fmaf((y - mean) * rstd, g_r, bt_r), 0.f);
            p ^= 1; sh_hs[p][tid] = hs_i;
            if (it == niter - 1 && t + 1 < T_STEPS && tid < DGI)
                sh_z[tid] = z_seq[((size_t)(t + 1) * BATCH + b) * DGI + tid];
            __syncthreads();
        }

        if (t < T_STEPS - 1) {
            const float* hcur = sh_hs[p];
            float h8[8];
            #pragma unroll
            for (int q = 0; q < 8; ++q) h8[q] = hcur[lane + 64 * q];
            for (int s = wave; s <= t; s += 8) {
                float d = 0.f;
                if (s == t) {
                    #pragma unroll
                    for (int q = 0; q < 8; ++q) d = fmaf(h8[q], h8[q], d);
                } else {
                    const float* vr = sh_hist[s];
                    #pragma unroll
                    for (int q = 0; q < 8; ++q) d = fmaf(vr[lane + 64 * q], h8[q], d);
                }
                #pragma unroll
                for (int off = 32; off > 0; off >>= 1) d += __shfl_xor(d, off, 64);
                if (lane == 0) {
                    if (s == t) { sh_G[t][t] = d; sh_coef[t] = ETA / (d + EPS_A); }
                    else        { sh_G[t][s] = d; sh_G[s][t] = d; }
                }
            }
            if (tid < t) sh_coef[tid] *= LAMBDA;
            sh_hist[t][tid] = hs_i;
        } else {
            out[(size_t)b * DHI + tid] = hs_i;
        }
    }
}

extern "C" void kernel_launch(void* const* d_in, const int* in_sizes, int n_in,
                              void* d_out, int out_size, void* d_ws, size_t ws_size,
                              hipStream_t stream) {
    const float* z_seq    = (const float*)d_in[0];
    const float* W_h      = (const float*)d_in[1];
    const float* W_g      = (const float*)d_in[2];
    const float* b_h      = (const float*)d_in[3];
    const float* gamma    = (const float*)d_in[4];
    const float* beta     = (const float*)d_in[5];
    const float* alpha_fw = (const float*)d_in[6];
    float* out = (float*)d_out;

    const size_t zp_elems  = (size_t)BATCH * T_STEPS * DHI;  // 6 MB
    const size_t wht_elems = (size_t)DHI * DHI;              // 1 MB
    const size_t needed = (zp_elems + wht_elems) * sizeof(float);
    if (ws_size >= needed) {
        float* zp  = (float*)d_ws;
        float* WhT = zp + zp_elems;
        float* dump = zp;   // ablation output sink (zp garbage-safe post-rnn_full)
        transpose_k<<<dim3(DHI / 32, DHI / 32), 256, 0, stream>>>(W_h, WhT, DHI, DHI);
        zproj_k<<<dim3(BATCH, T_STEPS / 8), 512, 0, stream>>>(z_seq, W_g, zp);
        // real kernel (validated output) first
        rnn_full<<<BATCH, DHI, 0, stream>>>(zp, WhT, b_h, gamma, beta, alpha_fw, out);
        // ablation dispatches (timing-only; outputs discarded into ws)
        rnn_nogemv<<<BATCH, DHI, 0, stream>>>(zp, WhT, b_h, gamma, beta, alpha_fw, dump);
        rnn_nodots<<<BATCH, DHI, 0, stream>>>(zp, WhT, b_h, gamma, beta, alpha_fw, dump);
        rnn_noscal<<<BATCH, DHI, 0, stream>>>(zp, WhT, b_h, gamma, beta, alpha_fw, dump);
        rnn_noln  <<<BATCH, DHI, 0, stream>>>(zp, WhT, b_h, gamma, beta, alpha_fw, dump);
    } else {
        corernn_fb<<<BATCH, DHI, 0, stream>>>(z_seq, W_h, W_g, b_h, gamma, beta,
                                              alpha_fw, out);
    }
}

// Round 8
// 409.321 us; speedup vs baseline: 4.0150x; 4.0150x over previous
//
#include <hip/hip_runtime.h>
#include <hip/hip_fp16.h>
#include <math.h>

#define T_STEPS 24
#define BATCH   128
#define DGI     256
#define DHI     512
#define S_ITERS 3
#define LAMBDA  0.95f
#define ETA     0.5f
#define EPS_A   1e-6f
#define LN_EPS  1e-5f
#define EPS_N   1e-6f
#define HIST_MAX 23   // at most T-1 stored rank-1 terms

// dot2: fp16x2 . fp16x2 + fp32 -> fp32 (v_dot2_f32_f16 when available)
static __device__ __forceinline__ float dot2(unsigned int a, unsigned int b, float c) {
#if __has_builtin(__builtin_amdgcn_fdot2)
    typedef _Float16 h2v __attribute__((ext_vector_type(2)));
    return __builtin_amdgcn_fdot2(__builtin_bit_cast(h2v, a),
                                  __builtin_bit_cast(h2v, b), c, false);
#else
    const __half2 ha = __builtin_bit_cast(__half2, a);
    const __half2 hb = __builtin_bit_cast(__half2, b);
    const float2 fa = __half22float2(ha);
    const float2 fb = __half22float2(hb);
    return fmaf(fa.x, fb.x, fmaf(fa.y, fb.y, c));
#endif
}

// ---------------------------------------------------------------------------
// Pack W_h into fp16 pairs along j: P[j2*512 + i] = {Wh[i][2j2], Wh[i][2j2+1]}
// grid DHI/2=256 blocks x 512 threads. Writes perfectly coalesced (runs once).
// ---------------------------------------------------------------------------
__global__ __launch_bounds__(512)
void pack_wh_k(const float* __restrict__ Wh, unsigned int* __restrict__ P) {
    const int j2 = blockIdx.x;
    const int i  = threadIdx.x;
    const float2 w = *(const float2*)(Wh + (size_t)i * DHI + 2 * j2);
    const __half2 h = __floats2half2_rn(w.x, w.y);
    P[(size_t)j2 * DHI + i] = __builtin_bit_cast(unsigned int, h);
}

// ---------------------------------------------------------------------------
// zproj[b][t][i] = sum_j Wg[i][j] * z[t][b][j]  (runs once, parallel)
// ---------------------------------------------------------------------------
__global__ __launch_bounds__(512)
void zproj_k(const float* __restrict__ z_seq, const float* __restrict__ Wg,
             float* __restrict__ zp) {
    __shared__ __align__(16) float sh_z[8][DGI];
    const int b    = blockIdx.x;
    const int t0   = blockIdx.y * 8;
    const int tid  = threadIdx.x;
    const int lane = tid & 63;
    const int wave = tid >> 6;
    {
        const float4* src =
            (const float4*)(z_seq + ((size_t)(t0 + wave) * BATCH + b) * DGI);
        ((float4*)sh_z[wave])[lane] = src[lane];
    }
    __syncthreads();

    float acc[8];
    #pragma unroll
    for (int tt = 0; tt < 8; ++tt) acc[tt] = 0.f;
    const float4* wrow = (const float4*)(Wg + (size_t)tid * DGI);
    #pragma unroll 4
    for (int j4 = 0; j4 < DGI / 4; ++j4) {
        const float4 w = wrow[j4];
        #pragma unroll
        for (int tt = 0; tt < 8; ++tt) {
            const float4 z = ((const float4*)sh_z[tt])[j4];
            acc[tt] = fmaf(w.x, z.x, acc[tt]);
            acc[tt] = fmaf(w.y, z.y, acc[tt]);
            acc[tt] = fmaf(w.z, z.z, acc[tt]);
            acc[tt] = fmaf(w.w, z.w, acc[tt]);
        }
    }
    #pragma unroll
    for (int tt = 0; tt < 8; ++tt)
        zp[((size_t)b * T_STEPS + (t0 + tt)) * DHI + tid] = acc[tt];
}

// ---------------------------------------------------------------------------
// Recurrence. One block per batch element, 512 threads.
// GEMV: thread (i4=tid&127, jg=tid>>7) owns outputs 4*i4..+3 over
// j in [jg*128,+128): 64 uint4 loads (4 half2 each) + 4 dot2 per load;
// h kept as packed half2 in sh_h2 (refreshed once per step via shfl pair).
// A is rank-1 factorized with an incrementally-maintained Gram matrix.
// ---------------------------------------------------------------------------
__global__ __launch_bounds__(512)
void rnn_fp16w(const float* __restrict__ zp,
               const unsigned int* __restrict__ P,   // packed WhT fp16 pairs
               const float* __restrict__ b_h,
               const float* __restrict__ gamma,
               const float* __restrict__ beta,
               const float* __restrict__ alpha_fw,
               float* __restrict__ out) {
    __shared__ __align__(16) float  sh_hist[HIST_MAX][DHI];
    __shared__ __align__(16) float  sh_hs[2][DHI];
    __shared__ __align__(16) float  sh_G[HIST_MAX][64];
    __shared__ __align__(16) float4 sh_part[4][128];       // GEMV jg-partials
    __shared__ __align__(16) unsigned int sh_h2[DHI / 2];  // h as half2 pairs
    __shared__ float  sh_coef[32];
    __shared__ float  sh_dot[32];
    __shared__ float2 sh_red[8];

    const int tid  = threadIdx.x;
    const int lane = tid & 63;
    const int wave = tid >> 6;
    const int b    = blockIdx.x;

    const float bh_r = b_h[tid];
    const float g_r  = gamma[tid];
    const float bt_r = beta[tid];

    float kpow;
    {
        const float a  = alpha_fw[0];
        const float ax = fabsf(a);
        const float sp = (ax > 20.f) ? ax : log1pf(expf(ax));
        kpow = (a >= 0.f) ? (1.f + sp) : (1.f / (1.f + sp));
    }

    for (int i = tid; i < HIST_MAX * 64; i += DHI) ((float*)sh_G)[i] = 0.f;
    __syncthreads();

    int   p = 0;
    float hs_i = 0.f, hbase_i = 0.f;

    for (int t = 0; t < T_STEPS; ++t) {
        const float zval = zp[((size_t)b * T_STEPS + t) * DHI + tid];
        if (t > 0) {
            const int i4 = tid & 127;
            const int jg = tid >> 7;
            const uint4* __restrict__ wp = (const uint4*)P;  // [j2*128 + i4]
            float4 acc = make_float4(0.f, 0.f, 0.f, 0.f);
            const int j2lo = jg * 64;
            #pragma unroll 8
            for (int jj = 0; jj < 64; ++jj) {
                const int j2 = j2lo + jj;
                const unsigned int hh = sh_h2[j2];           // broadcast
                const uint4 wv = wp[(size_t)j2 * 128 + i4];
                acc.x = dot2(wv.x, hh, acc.x);
                acc.y = dot2(wv.y, hh, acc.y);
                acc.z = dot2(wv.z, hh, acc.z);
                acc.w = dot2(wv.w, hh, acc.w);
            }
            sh_part[jg][i4] = acc;
            __syncthreads();                              // barrier A
            const float* pp = (const float*)sh_part;
            hbase_i = bh_r + zval +
                      ((pp[tid] + pp[512 + tid]) + (pp[1024 + tid] + pp[1536 + tid]));
        } else {
            hbase_i = bh_r + zval;                        // h0 == 0
        }
        hs_i = fmaxf(hbase_i, 0.f);
        p ^= 1;
        sh_hs[p][tid] = hs_i;
        __syncthreads();                                  // barrier 1

        const int niter = (t == 0) ? 1 : S_ITERS;
        for (int it = 0; it < niter; ++it) {
            const float* hcur = sh_hs[p];
            float h8[8];
            #pragma unroll
            for (int q = 0; q < 8; ++q) h8[q] = hcur[lane + 64 * q];

            // dots phase: wave-split over s in [0..t]; s==t is the self-dot
            for (int s = wave; s <= t; s += 8) {
                float d = 0.f;
                if (s == t) {
                    #pragma unroll
                    for (int q = 0; q < 8; ++q) d = fmaf(h8[q], h8[q], d);
                } else {
                    const float* vr = sh_hist[s];
                    #pragma unroll
                    for (int q = 0; q < 8; ++q) d = fmaf(vr[lane + 64 * q], h8[q], d);
                }
                #pragma unroll
                for (int off = 32; off > 0; off >>= 1) d += __shfl_xor(d, off, 64);
                if (lane == 0) sh_dot[s] = d;
            }
            __syncthreads();                              // barrier 2

            // scalar phase (per-thread redundant; broadcast LDS reads only)
            float dl = 0.f, w_l = 0.f;
            if (lane < t) { dl = sh_dot[lane]; w_l = sh_coef[lane] * dl; }

            float gsum = 0.f, Ah = 0.f;
            for (int s = 0; s < t; ++s) {
                const float ws = sh_coef[s] * sh_dot[s];  // uniform (broadcast)
                gsum = fmaf(ws, sh_G[s][lane], gsum);
                Ah   = fmaf(ws, sh_hist[s][tid], Ah);
            }
            float pa = w_l * dl;                          // -> h.Ah
            float pb = w_l * gsum;                        // -> |Ah|^2
            #pragma unroll
            for (int off = 32; off > 0; off >>= 1) {
                pa += __shfl_xor(pa, off, 64);
                pb += __shfl_xor(pb, off, 64);
            }
            const float n1 = fmaxf(sqrtf(sh_dot[t]), EPS_N);
            const float n2 = fmaxf(sqrtf(fmaxf(pb, 0.f)), EPS_N);
            float R = pa / (n1 * n2);
            R = fminf(fmaxf(R, 0.f), 1.f);
            const float alpha = 1.f - __powf(1.f - R, kpow);

            const float y = (1.f - alpha * alpha) * hbase_i + alpha * Ah;

            // LayerNorm reduction: one per-wave butterfly + one barrier
            float q0 = y, q1 = y * y;
            #pragma unroll
            for (int off = 32; off > 0; off >>= 1) {
                q0 += __shfl_xor(q0, off, 64);
                q1 += __shfl_xor(q1, off, 64);
            }
            if (lane == 0) sh_red[wave] = make_float2(q0, q1);
            __syncthreads();                              // barrier 3

            float s0 = 0.f, s1 = 0.f;
            #pragma unroll
            for (int w = 0; w < 8; ++w) {
                const float2 r = sh_red[w];
                s0 += r.x; s1 += r.y;
            }
            const float mean = s0 * (1.f / DHI);
            const float var  = fmaf(s1, 1.f / DHI, -mean * mean);
            const float rstd = rsqrtf(var + LN_EPS);
            hs_i = fmaxf(fmaf((y - mean) * rstd, g_r, bt_r), 0.f);
            p ^= 1;
            sh_hs[p][tid] = hs_i;
            // refresh packed-h for next step's GEMV (pair via lane shuffle)
            if (it == niter - 1 && t + 1 < T_STEPS) {
                const float partner = __shfl_xor(hs_i, 1);
                if (!(tid & 1)) {
                    const __half2 h2 = __floats2half2_rn(hs_i, partner);
                    sh_h2[tid >> 1] = __builtin_bit_cast(unsigned int, h2);
                }
            }
            __syncthreads();                              // barrier 4
        }

        if (t < T_STEPS - 1) {
            // history append: Gram row + coef; overlaps next GEMV
            const float* hcur = sh_hs[p];
            float h8[8];
            #pragma unroll
            for (int q = 0; q < 8; ++q) h8[q] = hcur[lane + 64 * q];
            for (int s = wave; s <= t; s += 8) {
                float d = 0.f;
                if (s == t) {
                    #pragma unroll
                    for (int q = 0; q < 8; ++q) d = fmaf(h8[q], h8[q], d);
                } else {
                    const float* vr = sh_hist[s];
                    #pragma unroll
                    for (int q = 0; q < 8; ++q) d = fmaf(vr[lane + 64 * q], h8[q], d);
                }
                #pragma unroll
                for (int off = 32; off > 0; off >>= 1) d += __shfl_xor(d, off, 64);
                if (lane == 0) {
                    if (s == t) {
                        sh_G[t][t] = d;
                        sh_coef[t] = ETA / (d + EPS_A);
                    } else {
                        sh_G[t][s] = d;
                        sh_G[s][t] = d;
                    }
                }
            }
            if (tid < t) sh_coef[tid] *= LAMBDA;
            sh_hist[t][tid] = hs_i;
        } else {
            out[(size_t)b * DHI + tid] = hs_i;
        }
    }
}

// ---------------------------------------------------------------------------
// Fallback (ws too small): fully self-contained fp32 row-major path.
// ---------------------------------------------------------------------------
__global__ __launch_bounds__(512)
void corernn_fb(const float* __restrict__ z_seq, const float* __restrict__ Wh,
                const float* __restrict__ Wg, const float* __restrict__ b_h,
                const float* __restrict__ gamma, const float* __restrict__ beta,
                const float* __restrict__ alpha_fw, float* __restrict__ out) {
    __shared__ __align__(16) float sh_hist[HIST_MAX][DHI];
    __shared__ __align__(16) float sh_hs[2][DHI];
    __shared__ __align__(16) float sh_G[HIST_MAX][64];
    __shared__ float  sh_coef[32];
    __shared__ float  sh_dot[32];
    __shared__ float2 sh_red[8];
    __shared__ __align__(16) float sh_z[DGI];

    const int tid  = threadIdx.x;
    const int lane = tid & 63;
    const int wave = tid >> 6;
    const int b    = blockIdx.x;
    const float bh_r = b_h[tid];
    const float g_r  = gamma[tid];
    const float bt_r = beta[tid];
    float kpow;
    {
        const float a  = alpha_fw[0];
        const float ax = fabsf(a);
        const float sp = (ax > 20.f) ? ax : log1pf(expf(ax));
        kpow = (a >= 0.f) ? (1.f + sp) : (1.f / (1.f + sp));
    }
    for (int i = tid; i < HIST_MAX * 64; i += DHI) ((float*)sh_G)[i] = 0.f;
    if (tid < DGI) sh_z[tid] = z_seq[(size_t)b * DGI + tid];
    __syncthreads();

    int p = 0;
    float hs_i = 0.f, hbase_i = 0.f;
    for (int t = 0; t < T_STEPS; ++t) {
        float a0 = bh_r, a1 = 0.f, a2 = 0.f, a3 = 0.f;
        {
            const float4* wrow = (const float4*)(Wg + (size_t)tid * DGI);
            const float4* z4   = (const float4*)sh_z;
            #pragma unroll 4
            for (int j4 = 0; j4 < DGI / 4; ++j4) {
                const float4 w = wrow[j4]; const float4 h = z4[j4];
                a0 = fmaf(w.x, h.x, a0); a1 = fmaf(w.y, h.y, a1);
                a2 = fmaf(w.z, h.z, a2); a3 = fmaf(w.w, h.w, a3);
            }
        }
        if (t > 0) {
            const float4* wrow = (const float4*)(Wh + (size_t)tid * DHI);
            const float4* h4   = (const float4*)sh_hs[p];
            #pragma unroll 4
            for (int j4 = 0; j4 < DHI / 4; ++j4) {
                const float4 w = wrow[j4]; const float4 h = h4[j4];
                a0 = fmaf(w.x, h.x, a0); a1 = fmaf(w.y, h.y, a1);
                a2 = fmaf(w.z, h.z, a2); a3 = fmaf(w.w, h.w, a3);
            }
        }
        hbase_i = (a0 + a1) + (a2 + a3);
        hs_i = fmaxf(hbase_i, 0.f);
        p ^= 1; sh_hs[p][tid] = hs_i;
        __syncthreads();

        const int niter = (t == 0) ? 1 : S_ITERS;
        for (int it = 0; it < niter; ++it) {
            const float* hcur = sh_hs[p];
            float h8[8];
            #pragma unroll
            for (int q = 0; q < 8; ++q) h8[q] = hcur[lane + 64 * q];
            for (int s = wave; s <= t; s += 8) {
                float d = 0.f;
                if (s == t) {
                    #pragma unroll
                    for (int q = 0; q < 8; ++q) d = fmaf(h8[q], h8[q], d);
                } else {
                    const float* vr = sh_hist[s];
                    #pragma unroll
                    for (int q = 0; q < 8; ++q) d = fmaf(vr[lane + 64 * q], h8[q], d);
                }
                #pragma unroll
                for (int off = 32; off > 0; off >>= 1) d += __shfl_xor(d, off, 64);
                if (lane == 0) sh_dot[s] = d;
            }
            __syncthreads();
            float dl = 0.f, w_l = 0.f;
            if (lane < t) { dl = sh_dot[lane]; w_l = sh_coef[lane] * dl; }
            float gsum = 0.f, Ah = 0.f;
            for (int s = 0; s < t; ++s) {
                const float ws = sh_coef[s] * sh_dot[s];
                gsum = fmaf(ws, sh_G[s][lane], gsum);
                Ah   = fmaf(ws, sh_hist[s][tid], Ah);
            }
            float pa = w_l * dl, pb = w_l * gsum;
            #pragma unroll
            for (int off = 32; off > 0; off >>= 1) {
                pa += __shfl_xor(pa, off, 64);
                pb += __shfl_xor(pb, off, 64);
            }
            const float n1 = fmaxf(sqrtf(sh_dot[t]), EPS_N);
            const float n2 = fmaxf(sqrtf(fmaxf(pb, 0.f)), EPS_N);
            float R = fminf(fmaxf(pa / (n1 * n2), 0.f), 1.f);
            const float alpha = 1.f - __powf(1.f - R, kpow);
            const float y = (1.f - alpha * alpha) * hbase_i + alpha * Ah;
            float q0 = y, q1 = y * y;
            #pragma unroll
            for (int off = 32; off > 0; off >>= 1) {
                q0 += __shfl_xor(q0, off, 64);
                q1 += __shfl_xor(q1, off, 64);
            }
            if (lane == 0) sh_red[wave] = make_float2(q0, q1);
            __syncthreads();
            float s0 = 0.f, s1 = 0.f;
            #pragma unroll
            for (int w = 0; w < 8; ++w) { const float2 r = sh_red[w]; s0 += r.x; s1 += r.y; }
            const float mean = s0 * (1.f / DHI);
            const float var  = fmaf(s1, 1.f / DHI, -mean * mean);
            const float rstd = rsqrtf(var + LN_EPS);
            hs_i = fmaxf(fmaf((y - mean) * rstd, g_r, bt_r), 0.f);
            p ^= 1; sh_hs[p][tid] = hs_i;
            if (it == niter - 1 && t + 1 < T_STEPS && tid < DGI)
                sh_z[tid] = z_seq[((size_t)(t + 1) * BATCH + b) * DGI + tid];
            __syncthreads();
        }

        if (t < T_STEPS - 1) {
            const float* hcur = sh_hs[p];
            float h8[8];
            #pragma unroll
            for (int q = 0; q < 8; ++q) h8[q] = hcur[lane + 64 * q];
            for (int s = wave; s <= t; s += 8) {
                float d = 0.f;
                if (s == t) {
                    #pragma unroll
                    for (int q = 0; q < 8; ++q) d = fmaf(h8[q], h8[q], d);
                } else {
                    const float* vr = sh_hist[s];
                    #pragma unroll
                    for (int q = 0; q < 8; ++q) d = fmaf(vr[lane + 64 * q], h8[q], d);
                }
                #pragma unroll
                for (int off = 32; off > 0; off >>= 1) d += __shfl_xor(d, off, 64);
                if (lane == 0) {
                    if (s == t) { sh_G[t][t] = d; sh_coef[t] = ETA / (d + EPS_A); }
                    else        { sh_G[t][s] = d; sh_G[s][t] = d; }
                }
            }
            if (tid < t) sh_coef[tid] *= LAMBDA;
            sh_hist[t][tid] = hs_i;
        } else {
            out[(size_t)b * DHI + tid] = hs_i;
        }
    }
}

extern "C" void kernel_launch(void* const* d_in, const int* in_sizes, int n_in,
                              void* d_out, int out_size, void* d_ws, size_t ws_size,
                              hipStream_t stream) {
    const float* z_seq    = (const float*)d_in[0];
    const float* W_h      = (const float*)d_in[1];
    const float* W_g      = (const float*)d_in[2];
    const float* b_h      = (const float*)d_in[3];
    const float* gamma    = (const float*)d_in[4];
    const float* beta     = (const float*)d_in[5];
    const float* alpha_fw = (const float*)d_in[6];
    float* out = (float*)d_out;

    const size_t zp_elems = (size_t)BATCH * T_STEPS * DHI;        // 6 MB fp32
    const size_t p_elems  = (size_t)(DHI / 2) * DHI;              // packed u32
    const size_t needed   = zp_elems * sizeof(float) + p_elems * sizeof(unsigned int);
    if (ws_size >= needed) {
        float* zp = (float*)d_ws;
        unsigned int* P = (unsigned int*)(zp + zp_elems);
        pack_wh_k<<<DHI / 2, DHI, 0, stream>>>(W_h, P);
        zproj_k<<<dim3(BATCH, T_STEPS / 8), 512, 0, stream>>>(z_seq, W_g, zp);
        rnn_fp16w<<<BATCH, DHI, 0, stream>>>(zp, P, b_h, gamma, beta, alpha_fw, out);
    } else {
        corernn_fb<<<BATCH, DHI, 0, stream>>>(z_seq, W_h, W_g, b_h, gamma, beta,
                                              alpha_fw, out);
    }
}

// Round 9
// 385.848 us; speedup vs baseline: 4.2592x; 1.0608x over previous
//
#include <hip/hip_runtime.h>
#include <hip/hip_fp16.h>
#include <math.h>

#define T_STEPS 24
#define BATCH   128
#define DGI     256
#define DHI     512
#define S_ITERS 3
#define LAMBDA  0.95f
#define ETA     0.5f
#define EPS_A   1e-6f
#define LN_EPS  1e-5f
#define EPS_N   1e-6f
#define HIST_MAX 23   // at most T-1 stored rank-1 terms
#define TPAD     28   // padded s-stride (112B: 16B-aligned, conflict-free b128)

// dot2: fp16x2 . fp16x2 + fp32 -> fp32 (v_dot2_f32_f16 when available)
static __device__ __forceinline__ float dot2(unsigned int a, unsigned int b, float c) {
#if __has_builtin(__builtin_amdgcn_fdot2)
    typedef _Float16 h2v __attribute__((ext_vector_type(2)));
    return __builtin_amdgcn_fdot2(__builtin_bit_cast(h2v, a),
                                  __builtin_bit_cast(h2v, b), c, false);
#else
    const __half2 ha = __builtin_bit_cast(__half2, a);
    const __half2 hb = __builtin_bit_cast(__half2, b);
    const float2 fa = __half22float2(ha);
    const float2 fb = __half22float2(hb);
    return fmaf(fa.x, fb.x, fmaf(fa.y, fb.y, c));
#endif
}

// ---------------------------------------------------------------------------
// Pack W_h into fp16 pairs along j: P[j2*512 + i] = {Wh[i][2j2], Wh[i][2j2+1]}
// ---------------------------------------------------------------------------
__global__ __launch_bounds__(512)
void pack_wh_k(const float* __restrict__ Wh, unsigned int* __restrict__ P) {
    const int j2 = blockIdx.x;
    const int i  = threadIdx.x;
    const float2 w = *(const float2*)(Wh + (size_t)i * DHI + 2 * j2);
    const __half2 h = __floats2half2_rn(w.x, w.y);
    P[(size_t)j2 * DHI + i] = __builtin_bit_cast(unsigned int, h);
}

// ---------------------------------------------------------------------------
// zproj[b][t][i] = sum_j Wg[i][j] * z[t][b][j]  (runs once, parallel)
// ---------------------------------------------------------------------------
__global__ __launch_bounds__(512)
void zproj_k(const float* __restrict__ z_seq, const float* __restrict__ Wg,
             float* __restrict__ zp) {
    __shared__ __align__(16) float sh_z[8][DGI];
    const int b    = blockIdx.x;
    const int t0   = blockIdx.y * 8;
    const int tid  = threadIdx.x;
    const int lane = tid & 63;
    const int wave = tid >> 6;
    {
        const float4* src =
            (const float4*)(z_seq + ((size_t)(t0 + wave) * BATCH + b) * DGI);
        ((float4*)sh_z[wave])[lane] = src[lane];
    }
    __syncthreads();

    float acc[8];
    #pragma unroll
    for (int tt = 0; tt < 8; ++tt) acc[tt] = 0.f;
    const float4* wrow = (const float4*)(Wg + (size_t)tid * DGI);
    #pragma unroll 4
    for (int j4 = 0; j4 < DGI / 4; ++j4) {
        const float4 w = wrow[j4];
        #pragma unroll
        for (int tt = 0; tt < 8; ++tt) {
            const float4 z = ((const float4*)sh_z[tt])[j4];
            acc[tt] = fmaf(w.x, z.x, acc[tt]);
            acc[tt] = fmaf(w.y, z.y, acc[tt]);
            acc[tt] = fmaf(w.z, z.z, acc[tt]);
            acc[tt] = fmaf(w.w, z.w, acc[tt]);
        }
    }
    #pragma unroll
    for (int tt = 0; tt < 8; ++tt)
        zp[((size_t)b * T_STEPS + (t0 + tt)) * DHI + tid] = acc[tt];
}

// ---------------------------------------------------------------------------
// Recurrence. One block per batch element, 512 threads.
// All hot LDS paths vectorized to b128 with conflict-free layouts:
//   - hist rows (dots): float4 pairs, bank-starts {0,4..28} spread
//   - histT[i][s] stride-28 (Ah loop): ceil(t/4) float4 reads
//   - G2[64][28] symmetric Gram (gsum): float4 rows, pre-zeroed
//   - coef/dot broadcast float4 pairs shared by gsum+Ah
// ---------------------------------------------------------------------------
__global__ __launch_bounds__(512)
void rnn_fp16w(const float* __restrict__ zp,
               const unsigned int* __restrict__ P,   // packed WhT fp16 pairs
               const float* __restrict__ b_h,
               const float* __restrict__ gamma,
               const float* __restrict__ beta,
               const float* __restrict__ alpha_fw,
               float* __restrict__ out) {
    __shared__ __align__(16) float  sh_hist[HIST_MAX][DHI];   // row-major (dots)
    __shared__ __align__(16) float  sh_histT[DHI][TPAD];      // transposed (Ah)
    __shared__ __align__(16) float  sh_G2[64][TPAD];          // symmetric Gram
    __shared__ __align__(16) float  sh_hs[2][DHI];
    __shared__ __align__(16) float4 sh_part[4][128];          // GEMV jg-partials
    __shared__ __align__(16) unsigned int sh_h2[DHI / 2];     // h as half2 pairs
    __shared__ __align__(16) float  sh_coef[32];
    __shared__ __align__(16) float  sh_dot[32];
    __shared__ float2 sh_red[8];

    const int tid  = threadIdx.x;
    const int lane = tid & 63;
    const int wave = tid >> 6;
    const int b    = blockIdx.x;

    const float bh_r = b_h[tid];
    const float g_r  = gamma[tid];
    const float bt_r = beta[tid];

    float kpow;
    {
        const float a  = alpha_fw[0];
        const float ax = fabsf(a);
        const float sp = (ax > 20.f) ? ax : log1pf(expf(ax));
        kpow = (a >= 0.f) ? (1.f + sp) : (1.f / (1.f + sp));
    }

    // pre-zero everything the ceil-group loops may touch (exact-0 tails)
    for (int i = tid; i < 64 * TPAD; i += DHI) ((float*)sh_G2)[i] = 0.f;
    #pragma unroll
    for (int k = 0; k < TPAD; ++k) sh_histT[tid][k] = 0.f;
    if (tid < 32) { sh_coef[tid] = 0.f; sh_dot[tid] = 0.f; }
    __syncthreads();

    int   p = 0;
    float hs_i = 0.f, hbase_i = 0.f;

    for (int t = 0; t < T_STEPS; ++t) {
        const float zval = zp[((size_t)b * T_STEPS + t) * DHI + tid];
        if (t > 0) {
            const int i4 = tid & 127;
            const int jg = tid >> 7;
            const uint4* __restrict__ wp = (const uint4*)P;  // [j2*128 + i4]
            float4 acc = make_float4(0.f, 0.f, 0.f, 0.f);
            const int j2lo = jg * 64;
            #pragma unroll 8
            for (int jj = 0; jj < 64; ++jj) {
                const int j2 = j2lo + jj;
                const unsigned int hh = sh_h2[j2];           // broadcast
                const uint4 wv = wp[(size_t)j2 * 128 + i4];
                acc.x = dot2(wv.x, hh, acc.x);
                acc.y = dot2(wv.y, hh, acc.y);
                acc.z = dot2(wv.z, hh, acc.z);
                acc.w = dot2(wv.w, hh, acc.w);
            }
            sh_part[jg][i4] = acc;
            __syncthreads();                              // barrier A
            const float* pp = (const float*)sh_part;
            hbase_i = bh_r + zval +
                      ((pp[tid] + pp[512 + tid]) + (pp[1024 + tid] + pp[1536 + tid]));
        } else {
            hbase_i = bh_r + zval;                        // h0 == 0
        }
        hs_i = fmaxf(hbase_i, 0.f);
        p ^= 1;
        sh_hs[p][tid] = hs_i;
        __syncthreads();                                  // barrier 1

        const int niter = (t == 0) ? 1 : S_ITERS;
        for (int it = 0; it < niter; ++it) {
            const float4* h4p = (const float4*)sh_hs[p];
            const float4 ha = h4p[lane];                  // j = 4*lane..
            const float4 hb = h4p[64 + lane];             // j = 256+4*lane..

            // dots phase: wave-split over s in [0..t]; b128 row reads
            for (int s = wave; s <= t; s += 8) {
                float d;
                if (s == t) {
                    d =            ha.x * ha.x;
                    d = fmaf(ha.y, ha.y, d); d = fmaf(ha.z, ha.z, d);
                    d = fmaf(ha.w, ha.w, d); d = fmaf(hb.x, hb.x, d);
                    d = fmaf(hb.y, hb.y, d); d = fmaf(hb.z, hb.z, d);
                    d = fmaf(hb.w, hb.w, d);
                } else {
                    const float4* vr4 = (const float4*)sh_hist[s];
                    const float4 va = vr4[lane];
                    const float4 vb = vr4[64 + lane];
                    d =            va.x * ha.x;
                    d = fmaf(va.y, ha.y, d); d = fmaf(va.z, ha.z, d);
                    d = fmaf(va.w, ha.w, d); d = fmaf(vb.x, hb.x, d);
                    d = fmaf(vb.y, hb.y, d); d = fmaf(vb.z, hb.z, d);
                    d = fmaf(vb.w, hb.w, d);
                }
                #pragma unroll
                for (int off = 32; off > 0; off >>= 1) d += __shfl_xor(d, off, 64);
                if (lane == 0) sh_dot[s] = d;
            }
            __syncthreads();                              // barrier 2

            // scalar phase: vectorized ws/G2/histT groups (tails are exact 0)
            float dl = 0.f, w_l = 0.f;
            if (lane < t) { dl = sh_dot[lane]; w_l = sh_coef[lane] * dl; }

            float gsum = 0.f, Ah = 0.f;
            {
                const float4* c4 = (const float4*)sh_coef;
                const float4* d4 = (const float4*)sh_dot;
                const float4* g4 = (const float4*)sh_G2[lane];
                const float4* a4 = (const float4*)sh_histT[tid];
                const int ng = (t + 3) >> 2;
                for (int g = 0; g < ng; ++g) {
                    const float4 cc = c4[g], dd = d4[g];
                    const float4 gg = g4[g], hv = a4[g];
                    const float w0 = cc.x * dd.x, w1 = cc.y * dd.y;
                    const float w2 = cc.z * dd.z, w3 = cc.w * dd.w;
                    gsum = fmaf(w0, gg.x, fmaf(w1, gg.y,
                           fmaf(w2, gg.z, fmaf(w3, gg.w, gsum))));
                    Ah   = fmaf(w0, hv.x, fmaf(w1, hv.y,
                           fmaf(w2, hv.z, fmaf(w3, hv.w, Ah))));
                }
            }
            float pa = w_l * dl;                          // -> h.Ah
            float pb = w_l * gsum;                        // -> |Ah|^2
            #pragma unroll
            for (int off = 32; off > 0; off >>= 1) {
                pa += __shfl_xor(pa, off, 64);
                pb += __shfl_xor(pb, off, 64);
            }
            const float n1 = fmaxf(sqrtf(sh_dot[t]), EPS_N);
            const float n2 = fmaxf(sqrtf(fmaxf(pb, 0.f)), EPS_N);
            float R = pa / (n1 * n2);
            R = fminf(fmaxf(R, 0.f), 1.f);
            const float alpha = 1.f - __powf(1.f - R, kpow);

            const float y = (1.f - alpha * alpha) * hbase_i + alpha * Ah;

            // LayerNorm reduction: one per-wave butterfly + one barrier
            float q0 = y, q1 = y * y;
            #pragma unroll
            for (int off = 32; off > 0; off >>= 1) {
                q0 += __shfl_xor(q0, off, 64);
                q1 += __shfl_xor(q1, off, 64);
            }
            if (lane == 0) sh_red[wave] = make_float2(q0, q1);
            __syncthreads();                              // barrier 3

            float s0 = 0.f, s1 = 0.f;
            #pragma unroll
            for (int w = 0; w < 8; ++w) {
                const float2 r = sh_red[w];
                s0 += r.x; s1 += r.y;
            }
            const float mean = s0 * (1.f / DHI);
            const float var  = fmaf(s1, 1.f / DHI, -mean * mean);
            const float rstd = rsqrtf(var + LN_EPS);
            hs_i = fmaxf(fmaf((y - mean) * rstd, g_r, bt_r), 0.f);
            p ^= 1;
            sh_hs[p][tid] = hs_i;
            // refresh packed-h for next step's GEMV (pair via lane shuffle)
            if (it == niter - 1 && t + 1 < T_STEPS) {
                const float partner = __shfl_xor(hs_i, 1);
                if (!(tid & 1)) {
                    const __half2 h2 = __floats2half2_rn(hs_i, partner);
                    sh_h2[tid >> 1] = __builtin_bit_cast(unsigned int, h2);
                }
            }
            __syncthreads();                              // barrier 4
        }

        if (t < T_STEPS - 1) {
            // history append: Gram row + coef + both hist layouts
            const float4* h4p = (const float4*)sh_hs[p];
            const float4 ha = h4p[lane];
            const float4 hb = h4p[64 + lane];
            for (int s = wave; s <= t; s += 8) {
                float d;
                if (s == t) {
                    d =            ha.x * ha.x;
                    d = fmaf(ha.y, ha.y, d); d = fmaf(ha.z, ha.z, d);
                    d = fmaf(ha.w, ha.w, d); d = fmaf(hb.x, hb.x, d);
                    d = fmaf(hb.y, hb.y, d); d = fmaf(hb.z, hb.z, d);
                    d = fmaf(hb.w, hb.w, d);
                } else {
                    const float4* vr4 = (const float4*)sh_hist[s];
                    const float4 va = vr4[lane];
                    const float4 vb = vr4[64 + lane];
                    d =            va.x * ha.x;
                    d = fmaf(va.y, ha.y, d); d = fmaf(va.z, ha.z, d);
                    d = fmaf(va.w, ha.w, d); d = fmaf(vb.x, hb.x, d);
                    d = fmaf(vb.y, hb.y, d); d = fmaf(vb.z, hb.z, d);
                    d = fmaf(vb.w, hb.w, d);
                }
                #pragma unroll
                for (int off = 32; off > 0; off >>= 1) d += __shfl_xor(d, off, 64);
                if (lane == 0) {
                    if (s == t) {
                        sh_G2[t][t] = d;
                        sh_coef[t]  = ETA / (d + EPS_A);
                    } else {
                        sh_G2[t][s] = d;
                        sh_G2[s][t] = d;
                    }
                }
            }
            if (tid < t) sh_coef[tid] *= LAMBDA;
            sh_hist[t][tid]   = hs_i;    // row-major (dots)
            sh_histT[tid][t]  = hs_i;    // transposed (Ah)
        } else {
            out[(size_t)b * DHI + tid] = hs_i;
        }
    }
}

// ---------------------------------------------------------------------------
// Fallback (ws too small): fully self-contained fp32 row-major path.
// ---------------------------------------------------------------------------
__global__ __launch_bounds__(512)
void corernn_fb(const float* __restrict__ z_seq, const float* __restrict__ Wh,
                const float* __restrict__ Wg, const float* __restrict__ b_h,
                const float* __restrict__ gamma, const float* __restrict__ beta,
                const float* __restrict__ alpha_fw, float* __restrict__ out) {
    __shared__ __align__(16) float sh_hist[HIST_MAX][DHI];
    __shared__ __align__(16) float sh_hs[2][DHI];
    __shared__ __align__(16) float sh_G[HIST_MAX][64];
    __shared__ float  sh_coef[32];
    __shared__ float  sh_dot[32];
    __shared__ float2 sh_red[8];
    __shared__ __align__(16) float sh_z[DGI];

    const int tid  = threadIdx.x;
    const int lane = tid & 63;
    const int wave = tid >> 6;
    const int b    = blockIdx.x;
    const float bh_r = b_h[tid];
    const float g_r  = gamma[tid];
    const float bt_r = beta[tid];
    float kpow;
    {
        const float a  = alpha_fw[0];
        const float ax = fabsf(a);
        const float sp = (ax > 20.f) ? ax : log1pf(expf(ax));
        kpow = (a >= 0.f) ? (1.f + sp) : (1.f / (1.f + sp));
    }
    for (int i = tid; i < HIST_MAX * 64; i += DHI) ((float*)sh_G)[i] = 0.f;
    if (tid < DGI) sh_z[tid] = z_seq[(size_t)b * DGI + tid];
    __syncthreads();

    int p = 0;
    float hs_i = 0.f, hbase_i = 0.f;
    for (int t = 0; t < T_STEPS; ++t) {
        float a0 = bh_r, a1 = 0.f, a2 = 0.f, a3 = 0.f;
        {
            const float4* wrow = (const float4*)(Wg + (size_t)tid * DGI);
            const float4* z4   = (const float4*)sh_z;
            #pragma unroll 4
            for (int j4 = 0; j4 < DGI / 4; ++j4) {
                const float4 w = wrow[j4]; const float4 h = z4[j4];
                a0 = fmaf(w.x, h.x, a0); a1 = fmaf(w.y, h.y, a1);
                a2 = fmaf(w.z, h.z, a2); a3 = fmaf(w.w, h.w, a3);
            }
        }
        if (t > 0) {
            const float4* wrow = (const float4*)(Wh + (size_t)tid * DHI);
            const float4* h4   = (const float4*)sh_hs[p];
            #pragma unroll 4
            for (int j4 = 0; j4 < DHI / 4; ++j4) {
                const float4 w = wrow[j4]; const float4 h = h4[j4];
                a0 = fmaf(w.x, h.x, a0); a1 = fmaf(w.y, h.y, a1);
                a2 = fmaf(w.z, h.z, a2); a3 = fmaf(w.w, h.w, a3);
            }
        }
        hbase_i = (a0 + a1) + (a2 + a3);
        hs_i = fmaxf(hbase_i, 0.f);
        p ^= 1; sh_hs[p][tid] = hs_i;
        __syncthreads();

        const int niter = (t == 0) ? 1 : S_ITERS;
        for (int it = 0; it < niter; ++it) {
            const float* hcur = sh_hs[p];
            float h8[8];
            #pragma unroll
            for (int q = 0; q < 8; ++q) h8[q] = hcur[lane + 64 * q];
            for (int s = wave; s <= t; s += 8) {
                float d = 0.f;
                if (s == t) {
                    #pragma unroll
                    for (int q = 0; q < 8; ++q) d = fmaf(h8[q], h8[q], d);
                } else {
                    const float* vr = sh_hist[s];
                    #pragma unroll
                    for (int q = 0; q < 8; ++q) d = fmaf(vr[lane + 64 * q], h8[q], d);
                }
                #pragma unroll
                for (int off = 32; off > 0; off >>= 1) d += __shfl_xor(d, off, 64);
                if (lane == 0) sh_dot[s] = d;
            }
            __syncthreads();
            float dl = 0.f, w_l = 0.f;
            if (lane < t) { dl = sh_dot[lane]; w_l = sh_coef[lane] * dl; }
            float gsum = 0.f, Ah = 0.f;
            for (int s = 0; s < t; ++s) {
                const float ws = sh_coef[s] * sh_dot[s];
                gsum = fmaf(ws, sh_G[s][lane], gsum);
                Ah   = fmaf(ws, sh_hist[s][tid], Ah);
            }
            float pa = w_l * dl, pb = w_l * gsum;
            #pragma unroll
            for (int off = 32; off > 0; off >>= 1) {
                pa += __shfl_xor(pa, off, 64);
                pb += __shfl_xor(pb, off, 64);
            }
            const float n1 = fmaxf(sqrtf(sh_dot[t]), EPS_N);
            const float n2 = fmaxf(sqrtf(fmaxf(pb, 0.f)), EPS_N);
            float R = fminf(fmaxf(pa / (n1 * n2), 0.f), 1.f);
            const float alpha = 1.f - __powf(1.f - R, kpow);
            const float y = (1.f - alpha * alpha) * hbase_i + alpha * Ah;
            float q0 = y, q1 = y * y;
            #pragma unroll
            for (int off = 32; off > 0; off >>= 1) {
                q0 += __shfl_xor(q0, off, 64);
                q1 += __shfl_xor(q1, off, 64);
            }
            if (lane == 0) sh_red[wave] = make_float2(q0, q1);
            __syncthreads();
            float s0 = 0.f, s1 = 0.f;
            #pragma unroll
            for (int w = 0; w < 8; ++w) { const float2 r = sh_red[w]; s0 += r.x; s1 += r.y; }
            const float mean = s0 * (1.f / DHI);
            const float var  = fmaf(s1, 1.f / DHI, -mean * mean);
            const float rstd = rsqrtf(var + LN_EPS);
            hs_i = fmaxf(fmaf((y - mean) * rstd, g_r, bt_r), 0.f);
            p ^= 1; sh_hs[p][tid] = hs_i;
            if (it == niter - 1 && t + 1 < T_STEPS && tid < DGI)
                sh_z[tid] = z_seq[((size_t)(t + 1) * BATCH + b) * DGI + tid];
            __syncthreads();
        }

        if (t < T_STEPS - 1) {
            const float* hcur = sh_hs[p];
            float h8[8];
            #pragma unroll
            for (int q = 0; q < 8; ++q) h8[q] = hcur[lane + 64 * q];
            for (int s = wave; s <= t; s += 8) {
                float d = 0.f;
                if (s == t) {
                    #pragma unroll
                    for (int q = 0; q < 8; ++q) d = fmaf(h8[q], h8[q], d);
                } else {
                    const float* vr = sh_hist[s];
                    #pragma unroll
                    for (int q = 0; q < 8; ++q) d = fmaf(vr[lane + 64 * q], h8[q], d);
                }
                #pragma unroll
                for (int off = 32; off > 0; off >>= 1) d += __shfl_xor(d, off, 64);
                if (lane == 0) {
                    if (s == t) { sh_G[t][t] = d; sh_coef[t] = ETA / (d + EPS_A); }
                    else        { sh_G[t][s] = d; sh_G[s][t] = d; }
                }
            }
            if (tid < t) sh_coef[tid] *= LAMBDA;
            sh_hist[t][tid] = hs_i;
        } else {
            out[(size_t)b * DHI + tid] = hs_i;
        }
    }
}

extern "C" void kernel_launch(void* const* d_in, const int* in_sizes, int n_in,
                              void* d_out, int out_size, void* d_ws, size_t ws_size,
                              hipStream_t stream) {
    const float* z_seq    = (const float*)d_in[0];
    const float* W_h      = (const float*)d_in[1];
    const float* W_g      = (const float*)d_in[2];
    const float* b_h      = (const float*)d_in[3];
    const float* gamma    = (const float*)d_in[4];
    const float* beta     = (const float*)d_in[5];
    const float* alpha_fw = (const float*)d_in[6];
    float* out = (float*)d_out;

    const size_t zp_elems = (size_t)BATCH * T_STEPS * DHI;        // 6 MB fp32
    const size_t p_elems  = (size_t)(DHI / 2) * DHI;              // packed u32
    const size_t needed   = zp_elems * sizeof(float) + p_elems * sizeof(unsigned int);
    if (ws_size >= needed) {
        float* zp = (float*)d_ws;
        unsigned int* P = (unsigned int*)(zp + zp_elems);
        pack_wh_k<<<DHI / 2, DHI, 0, stream>>>(W_h, P);
        zproj_k<<<dim3(BATCH, T_STEPS / 8), 512, 0, stream>>>(z_seq, W_g, zp);
        rnn_fp16w<<<BATCH, DHI, 0, stream>>>(zp, P, b_h, gamma, beta, alpha_fw, out);
    } else {
        corernn_fb<<<BATCH, DHI, 0, stream>>>(z_seq, W_h, W_g, b_h, gamma, beta,
                                              alpha_fw, out);
    }
}

// Round 10
// 366.255 us; speedup vs baseline: 4.4871x; 1.0535x over previous
//
#include <hip/hip_runtime.h>
#include <hip/hip_fp16.h>
#include <math.h>

#define T_STEPS 24
#define BATCH   128
#define DGI     256
#define DHI     512
#define S_ITERS 3
#define LAMBDA  0.95f
#define ETA     0.5f
#define EPS_A   1e-6f
#define LN_EPS  1e-5f
#define EPS_N   1e-6f
#define HIST_MAX 23
#define NG4      6    // ceil(24/4) groups of 4 s-slots

// dot2: fp16x2 . fp16x2 + fp32 -> fp32
static __device__ __forceinline__ float dot2(unsigned int a, unsigned int b, float c) {
#if __has_builtin(__builtin_amdgcn_fdot2)
    typedef _Float16 h2v __attribute__((ext_vector_type(2)));
    return __builtin_amdgcn_fdot2(__builtin_bit_cast(h2v, a),
                                  __builtin_bit_cast(h2v, b), c, false);
#else
    const __half2 ha = __builtin_bit_cast(__half2, a);
    const __half2 hb = __builtin_bit_cast(__half2, b);
    const float2 fa = __half22float2(ha);
    const float2 fb = __half22float2(hb);
    return fmaf(fa.x, fb.x, fmaf(fa.y, fb.y, c));
#endif
}

static __device__ __forceinline__ unsigned int rdlane_u(unsigned int v, int l) {
#if __has_builtin(__builtin_amdgcn_readlane)
    return __builtin_amdgcn_readlane(v, l);
#else
    return __shfl((int)v, l, 64);
#endif
}
static __device__ __forceinline__ float rdlane_f(float v, int l) {
    return __uint_as_float(rdlane_u(__float_as_uint(v), l));
}

static __device__ __forceinline__ float wsum(float v) {
    #pragma unroll
    for (int off = 32; off > 0; off >>= 1) v += __shfl_xor(v, off, 64);
    return v;
}
static __device__ __forceinline__ float dot8(float4 a, float4 b, float4 c, float4 d) {
    float r = a.x * c.x;
    r = fmaf(a.y, c.y, r); r = fmaf(a.z, c.z, r); r = fmaf(a.w, c.w, r);
    r = fmaf(b.x, d.x, r); r = fmaf(b.y, d.y, r); r = fmaf(b.z, d.z, r);
    r = fmaf(b.w, d.w, r);
    return r;
}
static __device__ __forceinline__ float sum8(float4 a, float4 b) {
    return ((a.x + a.y) + (a.z + a.w)) + ((b.x + b.y) + (b.z + b.w));
}

// ---------------------------------------------------------------------------
// Tiled transpose fp32: dst[c*R + r] = src[r*C + c]  (for WgT)
// ---------------------------------------------------------------------------
__global__ void transpose_k(const float* __restrict__ src, float* __restrict__ dst,
                            int R, int C) {
    __shared__ float tile[32][33];
    const int tx = threadIdx.x & 31;
    const int ty = threadIdx.x >> 5;
    const int c0 = blockIdx.x * 32;
    const int r0 = blockIdx.y * 32;
    #pragma unroll
    for (int i = 0; i < 32; i += 8)
        tile[ty + i][tx] = src[(size_t)(r0 + ty + i) * C + (c0 + tx)];
    __syncthreads();
    #pragma unroll
    for (int i = 0; i < 32; i += 8)
        dst[(size_t)(c0 + ty + i) * R + (r0 + tx)] = tile[tx][ty + i];
}

// ---------------------------------------------------------------------------
// Pack W_h fp16 pairs along j: P[j2*512 + i] = {Wh[i][2j2], Wh[i][2j2+1]}
// ---------------------------------------------------------------------------
__global__ __launch_bounds__(512)
void pack_wh_k(const float* __restrict__ Wh, unsigned int* __restrict__ P) {
    const int j2 = blockIdx.x;
    const int i  = threadIdx.x;
    const float2 w = *(const float2*)(Wh + (size_t)i * DHI + 2 * j2);
    const __half2 h = __floats2half2_rn(w.x, w.y);
    P[(size_t)j2 * DHI + i] = __builtin_bit_cast(unsigned int, h);
}

// ---------------------------------------------------------------------------
// zproj[b][t][i] = sum_j WgT[j][i] * z[t][b][j]  -- coalesced float4 weight
// loads, register z broadcast via readlane, LDS partial combine. fp32-exact.
// grid (BATCH, 3), 512 threads, 8 timesteps per block.
// ---------------------------------------------------------------------------
__global__ __launch_bounds__(512)
void zproj_k(const float* __restrict__ z_seq, const float* __restrict__ WgT,
             float* __restrict__ zp) {
    __shared__ __align__(16) float  sh_z[8][DGI];        // 8 KB
    __shared__ __align__(16) float4 sh_acc[8][4][128];   // 64 KB partials
    const int b    = blockIdx.x;
    const int t0   = blockIdx.y * 8;
    const int tid  = threadIdx.x;
    const int lane = tid & 63;
    const int wave = tid >> 6;
    {
        const float4* src =
            (const float4*)(z_seq + ((size_t)(t0 + wave) * BATCH + b) * DGI);
        ((float4*)sh_z[wave])[lane] = src[lane];
    }
    __syncthreads();

    const int i4  = tid & 127;
    const int jg  = tid >> 7;
    const int jlo = jg * 64;
    float zreg[8];
    #pragma unroll
    for (int tt = 0; tt < 8; ++tt) zreg[tt] = sh_z[tt][jlo + lane];

    float4 acc[8];
    #pragma unroll
    for (int tt = 0; tt < 8; ++tt) acc[tt] = make_float4(0.f, 0.f, 0.f, 0.f);

    const float4* w4 = (const float4*)WgT;   // [j*128 + i4]
    #pragma unroll 4
    for (int jj = 0; jj < 64; ++jj) {
        const float4 wv = w4[(size_t)(jlo + jj) * 128 + i4];
        #pragma unroll
        for (int tt = 0; tt < 8; ++tt) {
            const float zv = rdlane_f(zreg[tt], jj);
            acc[tt].x = fmaf(wv.x, zv, acc[tt].x);
            acc[tt].y = fmaf(wv.y, zv, acc[tt].y);
            acc[tt].z = fmaf(wv.z, zv, acc[tt].z);
            acc[tt].w = fmaf(wv.w, zv, acc[tt].w);
        }
    }
    #pragma unroll
    for (int tt = 0; tt < 8; ++tt) sh_acc[tt][jg][i4] = acc[tt];
    __syncthreads();

    const float* af = (const float*)sh_acc;
    #pragma unroll
    for (int tt = 0; tt < 8; ++tt) {
        const int o = tt * 4 * 512;
        const float v = (af[o + tid] + af[o + 512 + tid]) +
                        (af[o + 1024 + tid] + af[o + 1536 + tid]);
        zp[((size_t)b * T_STEPS + t0 + tt) * DHI + tid] = v;
    }
}

// ---------------------------------------------------------------------------
// Recurrence v3. One block per batch element, 512 threads.
// - GEMV: fp16 dot2, h broadcast via readlane (1 LDS read/step)
// - inner iter: dots -> barrier -> scalar (algebraic LN, 1 butterfly) -> barrier
// - conflict-free component-packed hT4/G4 layouts
// ---------------------------------------------------------------------------
__global__ __launch_bounds__(512)
void rnn_v3(const float* __restrict__ zp,
            const unsigned int* __restrict__ P,
            const float* __restrict__ b_h,
            const float* __restrict__ gamma,
            const float* __restrict__ beta,
            const float* __restrict__ alpha_fw,
            float* __restrict__ out) {
    __shared__ __align__(16) float  sh_hist[HIST_MAX][DHI];  // 46 KB row-major
    __shared__ __align__(16) float4 sh_hT4[NG4][DHI];        // 48 KB hist[4g+c][i]
    __shared__ __align__(16) float4 sh_G4[NG4][64];          // 6 KB  G[4g+c][s']
    __shared__ __align__(16) float  sh_hs[2][DHI];
    __shared__ __align__(16) float  sh_hb[DHI];
    __shared__ __align__(16) float4 sh_part[4][128];
    __shared__ __align__(16) unsigned int sh_h2[DHI / 2];
    __shared__ __align__(16) float  sh_coef[32];
    __shared__ __align__(16) float  sh_dot[32];
    __shared__ __align__(16) float  sh_dhb[32];   // hbase . hist_s
    __shared__ __align__(16) float  sh_rsum[32];  // rowsums of hist_s
    __shared__ float sh_misc[2];                  // S1 = sum(hb), S2 = sum(hb^2)

    const int tid  = threadIdx.x;
    const int lane = tid & 63;
    const int wave = tid >> 6;
    const int b    = blockIdx.x;

    const float bh_r = b_h[tid];
    const float g_r  = gamma[tid];
    const float bt_r = beta[tid];

    float kpow;
    {
        const float a  = alpha_fw[0];
        const float ax = fabsf(a);
        const float sp = (ax > 20.f) ? ax : log1pf(expf(ax));
        kpow = (a >= 0.f) ? (1.f + sp) : (1.f / (1.f + sp));
    }

    // pre-zero all zero-padded-tail structures (exact-0 tails, finite always)
    {
        const float4 z4 = make_float4(0.f, 0.f, 0.f, 0.f);
        for (int i = tid; i < NG4 * DHI; i += DHI) ((float4*)sh_hT4)[i] = z4;
        if (tid < NG4 * 64) ((float4*)sh_G4)[tid] = z4;
        if (tid < 32) { sh_coef[tid] = 0.f; sh_dot[tid] = 0.f;
                        sh_dhb[tid]  = 0.f; sh_rsum[tid] = 0.f; }
        if (tid < 2) sh_misc[tid] = 0.f;
    }
    __syncthreads();

    int   p = 0;
    float hs_i = 0.f, hbase_i = 0.f;
    const size_t zbase = (size_t)b * T_STEPS * DHI + tid;
    float zv = zp[zbase];   // t=0 prefetch

    for (int t = 0; t < T_STEPS; ++t) {
        // ---- GEMV: h_base = b_h + Wh.h + Wg.z
        if (t > 0) {
            const int i4 = tid & 127;
            const int jg = tid >> 7;
            const uint4* __restrict__ wp = (const uint4*)P;
            const unsigned int hreg = sh_h2[(jg << 6) | lane];  // wave's 64 h2
            const int base = (jg << 6) * 128 + i4;
            float4 acc = make_float4(0.f, 0.f, 0.f, 0.f);
            #pragma unroll 8
            for (int jj = 0; jj < 64; ++jj) {
                const unsigned int hh = rdlane_u(hreg, jj);     // SGPR broadcast
                const uint4 wv = wp[base + jj * 128];
                acc.x = dot2(wv.x, hh, acc.x);
                acc.y = dot2(wv.y, hh, acc.y);
                acc.z = dot2(wv.z, hh, acc.z);
                acc.w = dot2(wv.w, hh, acc.w);
            }
            sh_part[jg][i4] = acc;
            __syncthreads();                                  // barrier A
            const float* pp = (const float*)sh_part;
            hbase_i = bh_r + zv +
                      ((pp[tid] + pp[512 + tid]) + (pp[1024 + tid] + pp[1536 + tid]));
        } else {
            hbase_i = bh_r + zv;
        }
        sh_hb[tid] = hbase_i;
        hs_i = fmaxf(hbase_i, 0.f);
        p ^= 1;
        sh_hs[p][tid] = hs_i;
        __syncthreads();                                      // barrier 1

        // prefetch next step's zproj value (hidden under inner iters)
        if (t + 1 < T_STEPS) zv = zp[zbase + (size_t)(t + 1) * DHI];

        const int niter = (t == 0) ? 1 : S_ITERS;
        for (int it = 0; it < niter; ++it) {
            // ---- dots phase: wave-split over s in [0..t]
            {
                const float4* h4p = (const float4*)sh_hs[p];
                const float4 ha = h4p[lane], hc = h4p[64 + lane];
                float4 ba, bc;
                if (it == 0) {
                    const float4* b4p = (const float4*)sh_hb;
                    ba = b4p[lane]; bc = b4p[64 + lane];
                }
                for (int s = wave; s <= t; s += 8) {
                    if (s == t) {
                        float d = dot8(ha, hc, ha, hc);       // |h|^2
                        if (it == 0) {
                            float s1 = sum8(ba, bc);
                            float s2 = dot8(ba, bc, ba, bc);
                            d = wsum(d); s1 = wsum(s1); s2 = wsum(s2);
                            if (lane == 0) { sh_dot[t] = d;
                                             sh_misc[0] = s1; sh_misc[1] = s2; }
                        } else {
                            d = wsum(d);
                            if (lane == 0) sh_dot[t] = d;
                        }
                    } else {
                        const float4* v4 = (const float4*)sh_hist[s];
                        const float4 va = v4[lane], vc = v4[64 + lane];
                        float d = dot8(va, vc, ha, hc);
                        if (it == 0) {
                            float e = dot8(va, vc, ba, bc);   // hb . hist_s
                            d = wsum(d); e = wsum(e);
                            if (lane == 0) { sh_dot[s] = d; sh_dhb[s] = e; }
                        } else {
                            d = wsum(d);
                            if (lane == 0) sh_dot[s] = d;
                        }
                    }
                }
            }
            __syncthreads();                                  // barrier 2

            // ---- scalar phase: all sums from step-constant scalars
            float pa = 0.f, SA = 0.f, SHA = 0.f, gsum = 0.f, Ah = 0.f;
            {
                const float4* c4 = (const float4*)sh_coef;
                const float4* d4 = (const float4*)sh_dot;
                const float4* e4 = (const float4*)sh_dhb;
                const float4* r4 = (const float4*)sh_rsum;
                const int ng = (t + 4) >> 2;
                for (int g = 0; g < ng; ++g) {
                    const float4 cc = c4[g], dd = d4[g], ee = e4[g], rr = r4[g];
                    const float4 gg = sh_G4[g][lane];
                    const float4 hv = sh_hT4[g][tid];
                    const float w0 = cc.x * dd.x, w1 = cc.y * dd.y;
                    const float w2 = cc.z * dd.z, w3 = cc.w * dd.w;
                    pa   = fmaf(w0, dd.x, fmaf(w1, dd.y, fmaf(w2, dd.z, fmaf(w3, dd.w, pa))));
                    SA   = fmaf(w0, rr.x, fmaf(w1, rr.y, fmaf(w2, rr.z, fmaf(w3, rr.w, SA))));
                    SHA  = fmaf(w0, ee.x, fmaf(w1, ee.y, fmaf(w2, ee.z, fmaf(w3, ee.w, SHA))));
                    gsum = fmaf(w0, gg.x, fmaf(w1, gg.y, fmaf(w2, gg.z, fmaf(w3, gg.w, gsum))));
                    Ah   = fmaf(w0, hv.x, fmaf(w1, hv.y, fmaf(w2, hv.z, fmaf(w3, hv.w, Ah))));
                }
            }
            const float wl = (lane < 32) ? sh_coef[lane] * sh_dot[lane] : 0.f;
            const float pb = wsum(wl * gsum);                 // |Ah|^2 (one butterfly)

            const float n1 = fmaxf(sqrtf(sh_dot[t]), EPS_N);
            const float n2 = fmaxf(sqrtf(fmaxf(pb, 0.f)), EPS_N);
            float R = pa / (n1 * n2);
            R = fminf(fmaxf(R, 0.f), 1.f);
            const float alpha = 1.f - __powf(1.f - R, kpow);
            const float c = 1.f - alpha * alpha;

            const float S1 = sh_misc[0], S2 = sh_misc[1];
            const float mean = (c * S1 + alpha * SA) * (1.f / DHI);
            float var = (c * c * S2 + 2.f * c * alpha * SHA + alpha * alpha * pb)
                        * (1.f / DHI) - mean * mean;
            var = fmaxf(var, 0.f);
            const float rstd = rsqrtf(var + LN_EPS);

            const float y = fmaf(c, hbase_i, alpha * Ah);
            hs_i = fmaxf(fmaf((y - mean) * rstd, g_r, bt_r), 0.f);
            p ^= 1;
            sh_hs[p][tid] = hs_i;
            if (it == niter - 1 && t + 1 < T_STEPS) {
                const float partner = __shfl_xor(hs_i, 1);
                if (!(tid & 1)) {
                    const __half2 h2 = __floats2half2_rn(hs_i, partner);
                    sh_h2[tid >> 1] = __builtin_bit_cast(unsigned int, h2);
                }
            }
            __syncthreads();                                  // barrier 4
        }

        if (t < T_STEPS - 1) {
            // ---- append: Gram row + coef + rowsum + both hist layouts
            const float4* h4p = (const float4*)sh_hs[p];
            const float4 ha = h4p[lane], hc = h4p[64 + lane];
            for (int s = wave; s <= t; s += 8) {
                if (s == t) {
                    float d  = dot8(ha, hc, ha, hc);
                    float rs = sum8(ha, hc);
                    d = wsum(d); rs = wsum(rs);
                    if (lane == 0) {
                        ((float*)&sh_G4[t >> 2][t])[t & 3] = d;   // G[t][t]
                        sh_coef[t] = ETA / (d + EPS_A);
                        sh_rsum[t] = rs;
                    }
                } else {
                    const float4* v4 = (const float4*)sh_hist[s];
                    const float4 va = v4[lane], vc = v4[64 + lane];
                    float d = dot8(va, vc, ha, hc);
                    d = wsum(d);
                    if (lane == 0) {
                        ((float*)&sh_G4[t >> 2][s])[t & 3] = d;   // G[t][s]
                        ((float*)&sh_G4[s >> 2][t])[s & 3] = d;   // G[s][t]
                    }
                }
            }
            if (tid < t) sh_coef[tid] *= LAMBDA;
            sh_hist[t][tid] = hs_i;                        // row-major (dots)
            ((float*)&sh_hT4[t >> 2][tid])[t & 3] = hs_i;  // component-packed (Ah)
        } else {
            out[(size_t)b * DHI + tid] = hs_i;
        }
    }
}

// ---------------------------------------------------------------------------
// Fallback (ws too small): self-contained fp32 path (known-good, r6 structure).
// ---------------------------------------------------------------------------
__global__ __launch_bounds__(512)
void corernn_fb(const float* __restrict__ z_seq, const float* __restrict__ Wh,
                const float* __restrict__ Wg, const float* __restrict__ b_h,
                const float* __restrict__ gamma, const float* __restrict__ beta,
                const float* __restrict__ alpha_fw, float* __restrict__ out) {
    __shared__ __align__(16) float sh_hist[HIST_MAX][DHI];
    __shared__ __align__(16) float sh_hs[2][DHI];
    __shared__ __align__(16) float sh_G[HIST_MAX][64];
    __shared__ float  sh_coef[32];
    __shared__ float  sh_dot[32];
    __shared__ float2 sh_red[8];
    __shared__ __align__(16) float sh_z[DGI];

    const int tid  = threadIdx.x;
    const int lane = tid & 63;
    const int wave = tid >> 6;
    const int b    = blockIdx.x;
    const float bh_r = b_h[tid];
    const float g_r  = gamma[tid];
    const float bt_r = beta[tid];
    float kpow;
    {
        const float a  = alpha_fw[0];
        const float ax = fabsf(a);
        const float sp = (ax > 20.f) ? ax : log1pf(expf(ax));
        kpow = (a >= 0.f) ? (1.f + sp) : (1.f / (1.f + sp));
    }
    for (int i = tid; i < HIST_MAX * 64; i += DHI) ((float*)sh_G)[i] = 0.f;
    if (tid < DGI) sh_z[tid] = z_seq[(size_t)b * DGI + tid];
    __syncthreads();

    int p = 0;
    float hs_i = 0.f, hbase_i = 0.f;
    for (int t = 0; t < T_STEPS; ++t) {
        float a0 = bh_r, a1 = 0.f, a2 = 0.f, a3 = 0.f;
        {
            const float4* wrow = (const float4*)(Wg + (size_t)tid * DGI);
            const float4* z4   = (const float4*)sh_z;
            #pragma unroll 4
            for (int j4 = 0; j4 < DGI / 4; ++j4) {
                const float4 w = wrow[j4]; const float4 h = z4[j4];
                a0 = fmaf(w.x, h.x, a0); a1 = fmaf(w.y, h.y, a1);
                a2 = fmaf(w.z, h.z, a2); a3 = fmaf(w.w, h.w, a3);
            }
        }
        if (t > 0) {
            const float4* wrow = (const float4*)(Wh + (size_t)tid * DHI);
            const float4* h4   = (const float4*)sh_hs[p];
            #pragma unroll 4
            for (int j4 = 0; j4 < DHI / 4; ++j4) {
                const float4 w = wrow[j4]; const float4 h = h4[j4];
                a0 = fmaf(w.x, h.x, a0); a1 = fmaf(w.y, h.y, a1);
                a2 = fmaf(w.z, h.z, a2); a3 = fmaf(w.w, h.w, a3);
            }
        }
        hbase_i = (a0 + a1) + (a2 + a3);
        hs_i = fmaxf(hbase_i, 0.f);
        p ^= 1; sh_hs[p][tid] = hs_i;
        __syncthreads();

        const int niter = (t == 0) ? 1 : S_ITERS;
        for (int it = 0; it < niter; ++it) {
            const float* hcur = sh_hs[p];
            float h8[8];
            #pragma unroll
            for (int q = 0; q < 8; ++q) h8[q] = hcur[lane + 64 * q];
            for (int s = wave; s <= t; s += 8) {
                float d = 0.f;
                if (s == t) {
                    #pragma unroll
                    for (int q = 0; q < 8; ++q) d = fmaf(h8[q], h8[q], d);
                } else {
                    const float* vr = sh_hist[s];
                    #pragma unroll
                    for (int q = 0; q < 8; ++q) d = fmaf(vr[lane + 64 * q], h8[q], d);
                }
                #pragma unroll
                for (int off = 32; off > 0; off >>= 1) d += __shfl_xor(d, off, 64);
                if (lane == 0) sh_dot[s] = d;
            }
            __syncthreads();
            float dl = 0.f, w_l = 0.f;
            if (lane < t) { dl = sh_dot[lane]; w_l = sh_coef[lane] * dl; }
            float gsum = 0.f, Ah = 0.f;
            for (int s = 0; s < t; ++s) {
                const float ws = sh_coef[s] * sh_dot[s];
                gsum = fmaf(ws, sh_G[s][lane], gsum);
                Ah   = fmaf(ws, sh_hist[s][tid], Ah);
            }
            float pa = w_l * dl, pb = w_l * gsum;
            #pragma unroll
            for (int off = 32; off > 0; off >>= 1) {
                pa += __shfl_xor(pa, off, 64);
                pb += __shfl_xor(pb, off, 64);
            }
            const float n1 = fmaxf(sqrtf(sh_dot[t]), EPS_N);
            const float n2 = fmaxf(sqrtf(fmaxf(pb, 0.f)), EPS_N);
            float R = fminf(fmaxf(pa / (n1 * n2), 0.f), 1.f);
            const float alpha = 1.f - __powf(1.f - R, kpow);
            const float y = (1.f - alpha * alpha) * hbase_i + alpha * Ah;
            float q0 = y, q1 = y * y;
            #pragma unroll
            for (int off = 32; off > 0; off >>= 1) {
                q0 += __shfl_xor(q0, off, 64);
                q1 += __shfl_xor(q1, off, 64);
            }
            if (lane == 0) sh_red[wave] = make_float2(q0, q1);
            __syncthreads();
            float s0 = 0.f, s1 = 0.f;
            #pragma unroll
            for (int w = 0; w < 8; ++w) { const float2 r = sh_red[w]; s0 += r.x; s1 += r.y; }
            const float mean = s0 * (1.f / DHI);
            const float var  = fmaf(s1, 1.f / DHI, -mean * mean);
            const float rstd = rsqrtf(var + LN_EPS);
            hs_i = fmaxf(fmaf((y - mean) * rstd, g_r, bt_r), 0.f);
            p ^= 1; sh_hs[p][tid] = hs_i;
            if (it == niter - 1 && t + 1 < T_STEPS && tid < DGI)
                sh_z[tid] = z_seq[((size_t)(t + 1) * BATCH + b) * DGI + tid];
            __syncthreads();
        }

        if (t < T_STEPS - 1) {
            const float* hcur = sh_hs[p];
            float h8[8];
            #pragma unroll
            for (int q = 0; q < 8; ++q) h8[q] = hcur[lane + 64 * q];
            for (int s = wave; s <= t; s += 8) {
                float d = 0.f;
                if (s == t) {
                    #pragma unroll
                    for (int q = 0; q < 8; ++q) d = fmaf(h8[q], h8[q], d);
                } else {
                    const float* vr = sh_hist[s];
                    #pragma unroll
                    for (int q = 0; q < 8; ++q) d = fmaf(vr[lane + 64 * q], h8[q], d);
                }
                #pragma unroll
                for (int off = 32; off > 0; off >>= 1) d += __shfl_xor(d, off, 64);
                if (lane == 0) {
                    if (s == t) { sh_G[t][t] = d; sh_coef[t] = ETA / (d + EPS_A); }
                    else        { sh_G[t][s] = d; sh_G[s][t] = d; }
                }
            }
            if (tid < t) sh_coef[tid] *= LAMBDA;
            sh_hist[t][tid] = hs_i;
        } else {
            out[(size_t)b * DHI + tid] = hs_i;
        }
    }
}

extern "C" void kernel_launch(void* const* d_in, const int* in_sizes, int n_in,
                              void* d_out, int out_size, void* d_ws, size_t ws_size,
                              hipStream_t stream) {
    const float* z_seq    = (const float*)d_in[0];
    const float* W_h      = (const float*)d_in[1];
    const float* W_g      = (const float*)d_in[2];
    const float* b_h      = (const float*)d_in[3];
    const float* gamma    = (const float*)d_in[4];
    const float* beta     = (const float*)d_in[5];
    const float* alpha_fw = (const float*)d_in[6];
    float* out = (float*)d_out;

    const size_t zp_elems  = (size_t)BATCH * T_STEPS * DHI;  // 6 MB fp32
    const size_t wgt_elems = (size_t)DGI * DHI;              // 512 KB fp32
    const size_t p_elems   = (size_t)(DHI / 2) * DHI;        // 512 KB u32
    const size_t needed = (zp_elems + wgt_elems) * sizeof(float)
                        + p_elems * sizeof(unsigned int);
    if (ws_size >= needed) {
        float* zp  = (float*)d_ws;
        float* WgT = zp + zp_elems;
        unsigned int* P = (unsigned int*)(WgT + wgt_elems);
        transpose_k<<<dim3(DGI / 32, DHI / 32), 256, 0, stream>>>(W_g, WgT, DHI, DGI);
        pack_wh_k<<<DHI / 2, DHI, 0, stream>>>(W_h, P);
        zproj_k<<<dim3(BATCH, T_STEPS / 8), 512, 0, stream>>>(z_seq, WgT, zp);
        rnn_v3<<<BATCH, DHI, 0, stream>>>(zp, P, b_h, gamma, beta, alpha_fw, out);
    } else {
        corernn_fb<<<BATCH, DHI, 0, stream>>>(z_seq, W_h, W_g, b_h, gamma, beta,
                                              alpha_fw, out);
    }
}